// Round 1
// baseline (85.047 us; speedup 1.0000x reference)
//
#include <hip/hip_runtime.h>

#define GRID   64
#define CELLS  (GRID * GRID)
#define BATCH  4
#define NV     512
#define NNET   2000
#define MAXPIN 8
#define NB     32            // nets per sub-chunk (LDS tile)
#define NPART_MAX 16         // max private partial grids per batch

__device__ __forceinline__ float sigmoidf_fast(float z) {
    return 1.0f / (1.0f + __expf(-z));
}

// Each block owns `subs` sub-chunks of 32 nets, accumulates its private
// 64x64 partial in registers, and plain-stores it (no memset, no atomics).
__global__ __launch_bounds__(256)
void rudy_partial_kernel(const float* __restrict__ positions,
                         const float* __restrict__ pin_offsets,
                         const int*   __restrict__ net_to_pin,
                         const int*   __restrict__ pin_to_macro,
                         float* __restrict__ partial,
                         int subs) {
    const int pb = blockIdx.x;      // partial index within batch
    const int b  = blockIdx.y;
    const int t  = threadIdx.x;

    __shared__ float s_inx[NB][GRID];   // in_x * inv_size (folded)
    __shared__ float s_iny[NB][GRID];
    __shared__ float s_xmin[NB], s_xmax[NB], s_ymin[NB], s_ymax[NB], s_inv[NB];

    const int lane = t & 63;        // x coordinate
    const int w    = t >> 6;        // wave id: rows y = w*16 .. w*16+15

    float acc[16];
    #pragma unroll
    for (int k = 0; k < 16; ++k) acc[k] = 0.0f;

    const int base = pb * subs * NB;

    for (int sub = 0; sub < subs; ++sub) {
        const int n0 = base + sub * NB;

        // ---- A1: bbox per net, 8 lanes per net (shuffle reduce) ----
        {
            const int nl = t >> 3;      // local net 0..31
            const int j  = t & 7;       // pin slot
            const int n  = n0 + nl;
            int pi = (n < NNET) ? net_to_pin[n * MAXPIN + j] : -1;
            int sp = pi > 0 ? pi : 0;
            int v  = pin_to_macro[sp];
            float px = positions[(b * NV + v) * 2 + 0] + pin_offsets[sp * 2 + 0];
            float py = positions[(b * NV + v) * 2 + 1] + pin_offsets[sp * 2 + 1];
            bool valid = pi >= 0;
            float xmx = valid ? px : -1e9f;
            float xmn = valid ? px :  1e9f;
            float ymx = valid ? py : -1e9f;
            float ymn = valid ? py :  1e9f;
            #pragma unroll
            for (int off = 1; off < 8; off <<= 1) {
                xmx = fmaxf(xmx, __shfl_xor(xmx, off, 64));
                xmn = fminf(xmn, __shfl_xor(xmn, off, 64));
                ymx = fmaxf(ymx, __shfl_xor(ymx, off, 64));
                ymn = fminf(ymn, __shfl_xor(ymn, off, 64));
            }
            if (j == 0) {
                float xming = (xmn + 1.0f) * 31.5f;   // (v+1)*0.5*(M-1)
                float xmaxg = (xmx + 1.0f) * 31.5f;
                float yming = (ymn + 1.0f) * 31.5f;
                float ymaxg = (ymx + 1.0f) * 31.5f;
                float size = fmaxf((xmaxg - xming + 1.0f) * (ymaxg - yming + 1.0f), 1.0f);
                s_xmin[nl] = xming; s_xmax[nl] = xmaxg;
                s_ymin[nl] = yming; s_ymax[nl] = ymaxg;
                s_inv[nl]  = 1.0f / size;
            }
        }
        __syncthreads();

        // ---- A2: fill in_x (scaled by inv) / in_y — 4096 vals, 16/thread ----
        #pragma unroll
        for (int i = 0; i < 16; ++i) {
            int vv    = i * 256 + t;
            int n     = vv >> 7;          // net
            int rem   = vv & 127;
            int which = rem >> 6;         // 0 = x, 1 = y
            int coord = rem & 63;
            float c  = (float)coord;
            float lo = which ? s_ymin[n] : s_xmin[n];
            float hi = which ? s_ymax[n] : s_xmax[n];
            float val = sigmoidf_fast(2.0f * (c - lo + 0.5f)) *
                        sigmoidf_fast(2.0f * (hi - c + 0.5f));
            if (which) s_iny[n][coord] = val;
            else       s_inx[n][coord] = val * s_inv[n];
        }
        __syncthreads();

        // ---- C: rank-1 accumulate 16 cells/thread over NB nets ----
        for (int n = 0; n < NB; ++n) {
            float xv = s_inx[n][lane];
            const float4* iny4 = (const float4*)&s_iny[n][w * 16];
            #pragma unroll
            for (int k4 = 0; k4 < 4; ++k4) {
                float4 yv = iny4[k4];
                acc[k4 * 4 + 0] += yv.x * xv;
                acc[k4 * 4 + 1] += yv.y * xv;
                acc[k4 * 4 + 2] += yv.z * xv;
                acc[k4 * 4 + 3] += yv.w * xv;
            }
        }
        // No barrier needed here: next A1 writes only bbox scalars (not read
        // by C), and next A2 (which rewrites s_inx/s_iny) is behind the
        // post-A1 __syncthreads, which orders it after every thread's C.
    }

    // ---- plain coalesced store of this block's private partial ----
    float* dst = partial + ((size_t)b * gridDim.x + pb) * CELLS;
    #pragma unroll
    for (int k = 0; k < 16; ++k)
        dst[(w * 16 + k) * GRID + lane] = acc[k];
}

// One block per batch (1024 threads): sum npart partials into LDS, then
// separable 7-tap Gaussian + overflow penalty.
__global__ __launch_bounds__(1024)
void reduce_smooth_kernel(const float* __restrict__ partial,
                          float* __restrict__ out_penalty,
                          float* __restrict__ out_smooth,
                          int npart) {
    const int b = blockIdx.x;
    const int t = threadIdx.x;

    __shared__ float tile[CELLS];
    __shared__ float tmp [CELLS];
    __shared__ float red [16];

    // 1D gaussian, sigma=1.5, ksize=7, normalized (separable == normalized 2D)
    float g[7];
    {
        float s = 0.0f;
        #pragma unroll
        for (int i = 0; i < 7; ++i) {
            float d = (float)(i - 3);
            g[i] = expf(-d * d / 4.5f);
            s += g[i];
        }
        float inv = 1.0f / s;
        #pragma unroll
        for (int i = 0; i < 7; ++i) g[i] *= inv;
    }

    // ---- reduce partials: 4 cells/thread via float4, coalesced streaming ----
    const float4* src = (const float4*)(partial + (size_t)b * npart * CELLS);
    float4 a = {0.0f, 0.0f, 0.0f, 0.0f};
    #pragma unroll 4
    for (int p = 0; p < npart; ++p) {
        float4 v = src[p * (CELLS / 4) + t];
        a.x += v.x; a.y += v.y; a.z += v.z; a.w += v.w;
    }
    ((float4*)tile)[t] = a;
    __syncthreads();

    // ---- horizontal pass (zero padding), strided cells => conflict-free ----
    #pragma unroll
    for (int i = 0; i < 4; ++i) {
        int c = i * 1024 + t;
        int y = c >> 6, x = c & 63;
        float s = 0.0f;
        #pragma unroll
        for (int d = -3; d <= 3; ++d) {
            int xx = x + d;
            if (xx >= 0 && xx < GRID) s += g[d + 3] * tile[y * GRID + xx];
        }
        tmp[c] = s;
    }
    __syncthreads();

    // ---- vertical pass + outputs + penalty ----
    float local = 0.0f;
    #pragma unroll
    for (int i = 0; i < 4; ++i) {
        int c = i * 1024 + t;
        int y = c >> 6, x = c & 63;
        float s = 0.0f;
        #pragma unroll
        for (int d = -3; d <= 3; ++d) {
            int yy = y + d;
            if (yy >= 0 && yy < GRID) s += g[d + 3] * tmp[yy * GRID + x];
        }
        out_smooth[b * CELLS + c] = s;
        float ov = s - 1.0f;
        ov = ov > 0.0f ? ov : 0.0f;
        local += ov * ov;
    }

    #pragma unroll
    for (int off = 32; off > 0; off >>= 1) local += __shfl_down(local, off, 64);
    if ((t & 63) == 0) red[t >> 6] = local;
    __syncthreads();
    if (t == 0) {
        float s = 0.0f;
        #pragma unroll
        for (int i = 0; i < 16; ++i) s += red[i];
        out_penalty[b] = s;
    }
}

extern "C" void kernel_launch(void* const* d_in, const int* in_sizes, int n_in,
                              void* d_out, int out_size, void* d_ws, size_t ws_size,
                              hipStream_t stream) {
    const float* positions    = (const float*)d_in[0];
    const float* pin_offsets  = (const float*)d_in[1];
    const int*   net_to_pin   = (const int*)d_in[2];
    const int*   pin_to_macro = (const int*)d_in[3];
    float* out     = (float*)d_out;        // [0..3] penalty, [4..] rudy_smooth
    float* partial = (float*)d_ws;         // BATCH * npart * 4096 f32

    // Adapt partial count to available workspace (16 KB per partial per batch).
    int npart = (int)(ws_size / ((size_t)BATCH * CELLS * sizeof(float)));
    if (npart > NPART_MAX) npart = NPART_MAX;
    if (npart < 1) npart = 1;
    int nets_per_block = (NNET + npart - 1) / npart;
    int subs = (nets_per_block + NB - 1) / NB;

    rudy_partial_kernel<<<dim3(npart, BATCH), 256, 0, stream>>>(
        positions, pin_offsets, net_to_pin, pin_to_macro, partial, subs);
    reduce_smooth_kernel<<<BATCH, 1024, 0, stream>>>(partial, out, out + BATCH, npart);
}

// Round 2
// 82.234 us; speedup vs baseline: 1.0342x; 1.0342x over previous
//
#include <hip/hip_runtime.h>

#define GRID   64
#define CELLS  (GRID * GRID)
#define BATCH  4
#define NV     512
#define NNET   2000
#define MAXPIN 8
#define NB     32            // nets per sub-chunk (LDS tile)
#define NPART_MAX 63         // ceil(2000/32): one sub-chunk per block at full parallelism

__device__ __forceinline__ float sigmoidf_fast(float z) {
    return 1.0f / (1.0f + __expf(-z));
}

// Each block owns `subs` sub-chunks of 32 nets (subs==1 at full parallelism),
// accumulates its private 64x64 partial in registers, and plain-stores it
// (no memset dependency, no atomics).
__global__ __launch_bounds__(256)
void rudy_partial_kernel(const float* __restrict__ positions,
                         const float* __restrict__ pin_offsets,
                         const int*   __restrict__ net_to_pin,
                         const int*   __restrict__ pin_to_macro,
                         float* __restrict__ partial,
                         int subs) {
    const int pb = blockIdx.x;      // partial index within batch
    const int b  = blockIdx.y;
    const int t  = threadIdx.x;

    __shared__ float s_inx[NB][GRID];   // in_x * inv_size (folded)
    __shared__ float s_iny[NB][GRID];
    __shared__ float s_xmin[NB], s_xmax[NB], s_ymin[NB], s_ymax[NB], s_inv[NB];

    const int lane = t & 63;        // x coordinate
    const int w    = t >> 6;        // wave id: rows y = w*16 .. w*16+15

    float acc[16];
    #pragma unroll
    for (int k = 0; k < 16; ++k) acc[k] = 0.0f;

    const int base = pb * subs * NB;

    for (int sub = 0; sub < subs; ++sub) {
        const int n0 = base + sub * NB;

        // ---- A1: bbox per net, 8 lanes per net (shuffle reduce) ----
        {
            const int nl = t >> 3;      // local net 0..31
            const int j  = t & 7;       // pin slot
            const int n  = n0 + nl;
            int pi = (n < NNET) ? net_to_pin[n * MAXPIN + j] : -1;
            int sp = pi > 0 ? pi : 0;
            int v  = pin_to_macro[sp];
            float px = positions[(b * NV + v) * 2 + 0] + pin_offsets[sp * 2 + 0];
            float py = positions[(b * NV + v) * 2 + 1] + pin_offsets[sp * 2 + 1];
            bool valid = pi >= 0;
            float xmx = valid ? px : -1e9f;
            float xmn = valid ? px :  1e9f;
            float ymx = valid ? py : -1e9f;
            float ymn = valid ? py :  1e9f;
            #pragma unroll
            for (int off = 1; off < 8; off <<= 1) {
                xmx = fmaxf(xmx, __shfl_xor(xmx, off, 64));
                xmn = fminf(xmn, __shfl_xor(xmn, off, 64));
                ymx = fmaxf(ymx, __shfl_xor(ymx, off, 64));
                ymn = fminf(ymn, __shfl_xor(ymn, off, 64));
            }
            if (j == 0) {
                float xming = (xmn + 1.0f) * 31.5f;   // (v+1)*0.5*(M-1)
                float xmaxg = (xmx + 1.0f) * 31.5f;
                float yming = (ymn + 1.0f) * 31.5f;
                float ymaxg = (ymx + 1.0f) * 31.5f;
                float size = fmaxf((xmaxg - xming + 1.0f) * (ymaxg - yming + 1.0f), 1.0f);
                s_xmin[nl] = xming; s_xmax[nl] = xmaxg;
                s_ymin[nl] = yming; s_ymax[nl] = ymaxg;
                s_inv[nl]  = 1.0f / size;
            }
        }
        __syncthreads();

        // ---- A2: fill in_x (scaled by inv) / in_y — 4096 vals, 16/thread ----
        #pragma unroll
        for (int i = 0; i < 16; ++i) {
            int vv    = i * 256 + t;
            int n     = vv >> 7;          // net
            int rem   = vv & 127;
            int which = rem >> 6;         // 0 = x, 1 = y
            int coord = rem & 63;
            float c  = (float)coord;
            float lo = which ? s_ymin[n] : s_xmin[n];
            float hi = which ? s_ymax[n] : s_xmax[n];
            float val = sigmoidf_fast(2.0f * (c - lo + 0.5f)) *
                        sigmoidf_fast(2.0f * (hi - c + 0.5f));
            if (which) s_iny[n][coord] = val;
            else       s_inx[n][coord] = val * s_inv[n];
        }
        __syncthreads();

        // ---- C: rank-1 accumulate 16 cells/thread over NB nets ----
        for (int n = 0; n < NB; ++n) {
            float xv = s_inx[n][lane];
            const float4* iny4 = (const float4*)&s_iny[n][w * 16];
            #pragma unroll
            for (int k4 = 0; k4 < 4; ++k4) {
                float4 yv = iny4[k4];
                acc[k4 * 4 + 0] += yv.x * xv;
                acc[k4 * 4 + 1] += yv.y * xv;
                acc[k4 * 4 + 2] += yv.z * xv;
                acc[k4 * 4 + 3] += yv.w * xv;
            }
        }
        // Next A1 writes only bbox scalars (not read by C); next A2 (which
        // rewrites s_inx/s_iny) is behind the post-A1 __syncthreads, which
        // orders it after every thread's C. So no extra barrier here.
    }

    // ---- plain coalesced store of this block's private partial ----
    float* dst = partial + ((size_t)b * gridDim.x + pb) * CELLS;
    #pragma unroll
    for (int k = 0; k < 16; ++k)
        dst[(w * 16 + k) * GRID + lane] = acc[k];
}

// One block per batch (1024 threads): sum npart partials into LDS, then
// separable 7-tap Gaussian + overflow penalty.
__global__ __launch_bounds__(1024)
void reduce_smooth_kernel(const float* __restrict__ partial,
                          float* __restrict__ out_penalty,
                          float* __restrict__ out_smooth,
                          int npart) {
    const int b = blockIdx.x;
    const int t = threadIdx.x;

    __shared__ float tile[CELLS];
    __shared__ float tmp [CELLS];
    __shared__ float red [16];

    // 1D gaussian, sigma=1.5, ksize=7, normalized (separable == normalized 2D)
    float g[7];
    {
        float s = 0.0f;
        #pragma unroll
        for (int i = 0; i < 7; ++i) {
            float d = (float)(i - 3);
            g[i] = expf(-d * d / 4.5f);
            s += g[i];
        }
        float inv = 1.0f / s;
        #pragma unroll
        for (int i = 0; i < 7; ++i) g[i] *= inv;
    }

    // ---- reduce partials: 4 cells/thread via float4, coalesced streaming ----
    const float4* src = (const float4*)(partial + (size_t)b * npart * CELLS);
    float4 a = {0.0f, 0.0f, 0.0f, 0.0f};
    #pragma unroll 4
    for (int p = 0; p < npart; ++p) {
        float4 v = src[p * (CELLS / 4) + t];
        a.x += v.x; a.y += v.y; a.z += v.z; a.w += v.w;
    }
    ((float4*)tile)[t] = a;
    __syncthreads();

    // ---- horizontal pass (zero padding), strided cells => conflict-free ----
    #pragma unroll
    for (int i = 0; i < 4; ++i) {
        int c = i * 1024 + t;
        int y = c >> 6, x = c & 63;
        float s = 0.0f;
        #pragma unroll
        for (int d = -3; d <= 3; ++d) {
            int xx = x + d;
            if (xx >= 0 && xx < GRID) s += g[d + 3] * tile[y * GRID + xx];
        }
        tmp[c] = s;
    }
    __syncthreads();

    // ---- vertical pass + outputs + penalty ----
    float local = 0.0f;
    #pragma unroll
    for (int i = 0; i < 4; ++i) {
        int c = i * 1024 + t;
        int y = c >> 6, x = c & 63;
        float s = 0.0f;
        #pragma unroll
        for (int d = -3; d <= 3; ++d) {
            int yy = y + d;
            if (yy >= 0 && yy < GRID) s += g[d + 3] * tmp[yy * GRID + x];
        }
        out_smooth[b * CELLS + c] = s;
        float ov = s - 1.0f;
        ov = ov > 0.0f ? ov : 0.0f;
        local += ov * ov;
    }

    #pragma unroll
    for (int off = 32; off > 0; off >>= 1) local += __shfl_down(local, off, 64);
    if ((t & 63) == 0) red[t >> 6] = local;
    __syncthreads();
    if (t == 0) {
        float s = 0.0f;
        #pragma unroll
        for (int i = 0; i < 16; ++i) s += red[i];
        out_penalty[b] = s;
    }
}

extern "C" void kernel_launch(void* const* d_in, const int* in_sizes, int n_in,
                              void* d_out, int out_size, void* d_ws, size_t ws_size,
                              hipStream_t stream) {
    const float* positions    = (const float*)d_in[0];
    const float* pin_offsets  = (const float*)d_in[1];
    const int*   net_to_pin   = (const int*)d_in[2];
    const int*   pin_to_macro = (const int*)d_in[3];
    float* out     = (float*)d_out;        // [0..3] penalty, [4..] rudy_smooth
    float* partial = (float*)d_ws;         // BATCH * npart * 4096 f32

    // Full parallelism: one 32-net sub-chunk per block (needs ~4 MB of ws).
    int npart = (int)(ws_size / ((size_t)BATCH * CELLS * sizeof(float)));
    if (npart > NPART_MAX) npart = NPART_MAX;
    if (npart < 1) npart = 1;
    int nets_per_block = (NNET + npart - 1) / npart;
    int subs = (nets_per_block + NB - 1) / NB;

    rudy_partial_kernel<<<dim3(npart, BATCH), 256, 0, stream>>>(
        positions, pin_offsets, net_to_pin, pin_to_macro, partial, subs);
    reduce_smooth_kernel<<<BATCH, 1024, 0, stream>>>(partial, out, out + BATCH, npart);
}

// Round 3
// 76.397 us; speedup vs baseline: 1.1132x; 1.0764x over previous
//
#include <hip/hip_runtime.h>

#define GRID   64
#define CELLS  (GRID * GRID)
#define BATCH  4
#define NV     512
#define NNET   2000
#define MAXPIN 8
#define NB     32            // nets per sub-chunk (LDS tile)
#define NPART_MAX 63         // ceil(2000/32): one sub-chunk per block at full parallelism

__device__ __forceinline__ float sigmoidf_fast(float z) {
    return 1.0f / (1.0f + __expf(-z));
}

// Stage 1: each block owns `subs` sub-chunks of 32 nets (subs==1 at full
// parallelism), accumulates its private 64x64 partial in registers, and
// plain-stores it (no memset dependency, no atomics).
__global__ __launch_bounds__(256)
void rudy_partial_kernel(const float* __restrict__ positions,
                         const float* __restrict__ pin_offsets,
                         const int*   __restrict__ net_to_pin,
                         const int*   __restrict__ pin_to_macro,
                         float* __restrict__ partial,
                         int subs) {
    const int pb = blockIdx.x;      // partial index within batch
    const int b  = blockIdx.y;
    const int t  = threadIdx.x;

    __shared__ float s_inx[NB][GRID];   // in_x * inv_size (folded)
    __shared__ float s_iny[NB][GRID];
    __shared__ float s_xmin[NB], s_xmax[NB], s_ymin[NB], s_ymax[NB], s_inv[NB];

    const int lane = t & 63;        // x coordinate
    const int w    = t >> 6;        // wave id: rows y = w*16 .. w*16+15

    float acc[16];
    #pragma unroll
    for (int k = 0; k < 16; ++k) acc[k] = 0.0f;

    const int base = pb * subs * NB;

    for (int sub = 0; sub < subs; ++sub) {
        const int n0 = base + sub * NB;

        // ---- A1: bbox per net, 8 lanes per net (shuffle reduce) ----
        {
            const int nl = t >> 3;      // local net 0..31
            const int j  = t & 7;       // pin slot
            const int n  = n0 + nl;
            int pi = (n < NNET) ? net_to_pin[n * MAXPIN + j] : -1;
            int sp = pi > 0 ? pi : 0;
            int v  = pin_to_macro[sp];
            float px = positions[(b * NV + v) * 2 + 0] + pin_offsets[sp * 2 + 0];
            float py = positions[(b * NV + v) * 2 + 1] + pin_offsets[sp * 2 + 1];
            bool valid = pi >= 0;
            float xmx = valid ? px : -1e9f;
            float xmn = valid ? px :  1e9f;
            float ymx = valid ? py : -1e9f;
            float ymn = valid ? py :  1e9f;
            #pragma unroll
            for (int off = 1; off < 8; off <<= 1) {
                xmx = fmaxf(xmx, __shfl_xor(xmx, off, 64));
                xmn = fminf(xmn, __shfl_xor(xmn, off, 64));
                ymx = fmaxf(ymx, __shfl_xor(ymx, off, 64));
                ymn = fminf(ymn, __shfl_xor(ymn, off, 64));
            }
            if (j == 0) {
                float xming = (xmn + 1.0f) * 31.5f;   // (v+1)*0.5*(M-1)
                float xmaxg = (xmx + 1.0f) * 31.5f;
                float yming = (ymn + 1.0f) * 31.5f;
                float ymaxg = (ymx + 1.0f) * 31.5f;
                float size = fmaxf((xmaxg - xming + 1.0f) * (ymaxg - yming + 1.0f), 1.0f);
                s_xmin[nl] = xming; s_xmax[nl] = xmaxg;
                s_ymin[nl] = yming; s_ymax[nl] = ymaxg;
                s_inv[nl]  = 1.0f / size;
            }
        }
        __syncthreads();

        // ---- A2: fill in_x (scaled by inv) / in_y — 4096 vals, 16/thread ----
        #pragma unroll
        for (int i = 0; i < 16; ++i) {
            int vv    = i * 256 + t;
            int n     = vv >> 7;          // net
            int rem   = vv & 127;
            int which = rem >> 6;         // 0 = x, 1 = y
            int coord = rem & 63;
            float c  = (float)coord;
            float lo = which ? s_ymin[n] : s_xmin[n];
            float hi = which ? s_ymax[n] : s_xmax[n];
            float val = sigmoidf_fast(2.0f * (c - lo + 0.5f)) *
                        sigmoidf_fast(2.0f * (hi - c + 0.5f));
            if (which) s_iny[n][coord] = val;
            else       s_inx[n][coord] = val * s_inv[n];
        }
        __syncthreads();

        // ---- C: rank-1 accumulate 16 cells/thread over NB nets ----
        for (int n = 0; n < NB; ++n) {
            float xv = s_inx[n][lane];
            const float4* iny4 = (const float4*)&s_iny[n][w * 16];
            #pragma unroll
            for (int k4 = 0; k4 < 4; ++k4) {
                float4 yv = iny4[k4];
                acc[k4 * 4 + 0] += yv.x * xv;
                acc[k4 * 4 + 1] += yv.y * xv;
                acc[k4 * 4 + 2] += yv.z * xv;
                acc[k4 * 4 + 3] += yv.w * xv;
            }
        }
        // Next A1 writes only bbox scalars (not read by C); next A2 (which
        // rewrites s_inx/s_iny) is behind the post-A1 __syncthreads.
    }

    // ---- plain coalesced store of this block's private partial ----
    float* dst = partial + ((size_t)b * gridDim.x + pb) * CELLS;
    #pragma unroll
    for (int k = 0; k < 16; ++k)
        dst[(w * 16 + k) * GRID + lane] = acc[k];
}

// Stage 2: parallel tree-less reduction of npart partials -> rudy grid.
// grid (4, BATCH), 256 threads: each thread owns one float4 (16 cells/块
// quarter of the 4096-cell grid per block), coalesced 1KB/wave/partial.
__global__ __launch_bounds__(256)
void reduce_kernel(const float* __restrict__ partial,
                   float* __restrict__ rudy,
                   int npart) {
    const int blk = blockIdx.x;     // cell quarter 0..3
    const int b   = blockIdx.y;
    const int t   = threadIdx.x;
    const int idx = blk * 256 + t;  // float4 index within grid (0..1023)

    const float4* src = (const float4*)(partial + (size_t)b * npart * CELLS);
    float4 a = {0.0f, 0.0f, 0.0f, 0.0f};
    #pragma unroll 4
    for (int p = 0; p < npart; ++p) {
        float4 v = src[(size_t)p * (CELLS / 4) + idx];
        a.x += v.x; a.y += v.y; a.z += v.z; a.w += v.w;
    }
    ((float4*)(rudy + (size_t)b * CELLS))[idx] = a;
}

// Stage 3: one block per batch (1024 threads): separable 7-tap Gaussian
// on the reduced 16KB grid + overflow penalty.
__global__ __launch_bounds__(1024)
void smooth_penalty_kernel(const float* __restrict__ rudy,
                           float* __restrict__ out_penalty,
                           float* __restrict__ out_smooth) {
    const int b = blockIdx.x;
    const int t = threadIdx.x;

    __shared__ float tile[CELLS];
    __shared__ float tmp [CELLS];
    __shared__ float red [16];

    // 1D gaussian, sigma=1.5, ksize=7, normalized (separable == normalized 2D)
    float g[7];
    {
        float s = 0.0f;
        #pragma unroll
        for (int i = 0; i < 7; ++i) {
            float d = (float)(i - 3);
            g[i] = expf(-d * d / 4.5f);
            s += g[i];
        }
        float inv = 1.0f / s;
        #pragma unroll
        for (int i = 0; i < 7; ++i) g[i] *= inv;
    }

    ((float4*)tile)[t] = ((const float4*)(rudy + (size_t)b * CELLS))[t];
    __syncthreads();

    // horizontal pass (zero padding)
    #pragma unroll
    for (int i = 0; i < 4; ++i) {
        int c = i * 1024 + t;
        int y = c >> 6, x = c & 63;
        float s = 0.0f;
        #pragma unroll
        for (int d = -3; d <= 3; ++d) {
            int xx = x + d;
            if (xx >= 0 && xx < GRID) s += g[d + 3] * tile[y * GRID + xx];
        }
        tmp[c] = s;
    }
    __syncthreads();

    // vertical pass + outputs + penalty
    float local = 0.0f;
    #pragma unroll
    for (int i = 0; i < 4; ++i) {
        int c = i * 1024 + t;
        int y = c >> 6, x = c & 63;
        float s = 0.0f;
        #pragma unroll
        for (int d = -3; d <= 3; ++d) {
            int yy = y + d;
            if (yy >= 0 && yy < GRID) s += g[d + 3] * tmp[yy * GRID + x];
        }
        out_smooth[b * CELLS + c] = s;
        float ov = s - 1.0f;
        ov = ov > 0.0f ? ov : 0.0f;
        local += ov * ov;
    }

    #pragma unroll
    for (int off = 32; off > 0; off >>= 1) local += __shfl_down(local, off, 64);
    if ((t & 63) == 0) red[t >> 6] = local;
    __syncthreads();
    if (t == 0) {
        float s = 0.0f;
        #pragma unroll
        for (int i = 0; i < 16; ++i) s += red[i];
        out_penalty[b] = s;
    }
}

extern "C" void kernel_launch(void* const* d_in, const int* in_sizes, int n_in,
                              void* d_out, int out_size, void* d_ws, size_t ws_size,
                              hipStream_t stream) {
    const float* positions    = (const float*)d_in[0];
    const float* pin_offsets  = (const float*)d_in[1];
    const int*   net_to_pin   = (const int*)d_in[2];
    const int*   pin_to_macro = (const int*)d_in[3];
    float* out     = (float*)d_out;        // [0..3] penalty, [4..] rudy_smooth
    float* partial = (float*)d_ws;         // BATCH * npart * 4096 f32

    // Full parallelism: one 32-net sub-chunk per block (needs ~4 MB of ws).
    size_t need_per_part = (size_t)BATCH * CELLS * sizeof(float);
    // Reserve space for the reduced rudy grid (one partial-slot worth).
    int npart = (int)(ws_size / need_per_part) - 1;
    if (npart > NPART_MAX) npart = NPART_MAX;
    if (npart < 1) npart = 1;
    int nets_per_block = (NNET + npart - 1) / npart;
    int subs = (nets_per_block + NB - 1) / NB;

    float* rudy = partial + (size_t)BATCH * npart * CELLS;

    rudy_partial_kernel<<<dim3(npart, BATCH), 256, 0, stream>>>(
        positions, pin_offsets, net_to_pin, pin_to_macro, partial, subs);
    reduce_kernel<<<dim3(4, BATCH), 256, 0, stream>>>(partial, rudy, npart);
    smooth_penalty_kernel<<<BATCH, 1024, 0, stream>>>(rudy, out, out + BATCH);
}

// Round 4
// 74.651 us; speedup vs baseline: 1.1393x; 1.0234x over previous
//
#include <hip/hip_runtime.h>

#define GRID   64
#define CELLS  (GRID * GRID)
#define BATCH  4
#define NV     512
#define NNET   2000
#define MAXPIN 8
#define NB     32            // nets per block (one sub-chunk, no serial loop)
#define NPART  63            // ceil(2000/32)

// sigma(a)*sigma(b) = 1 / ((1+e^-a)(1+e^-b)) : 2 exp, 1 divide
__device__ __forceinline__ float sig2(float a, float b) {
    float e1 = __expf(-a);
    float e2 = __expf(-b);
    return 1.0f / ((1.0f + e1) * (1.0f + e2));
}

// Stage A: 252 blocks x 512 threads (2 waves/SIMD). Each block owns 32 nets,
// accumulates a private 64x64 partial in registers (8 cells/thread), stores it
// plain (no memset, no atomics). Block pb==0 also zero-inits out_penalty[b].
__global__ __launch_bounds__(512)
void rudy_partial_kernel(const float* __restrict__ positions,
                         const float* __restrict__ pin_offsets,
                         const int*   __restrict__ net_to_pin,
                         const int*   __restrict__ pin_to_macro,
                         float* __restrict__ partial,
                         float* __restrict__ out_penalty) {
    const int pb = blockIdx.x;      // partial index within batch (0..62)
    const int b  = blockIdx.y;
    const int t  = threadIdx.x;

    if (pb == 0 && t == 0) out_penalty[b] = 0.0f;

    __shared__ float s_inx[NB][GRID];   // in_x * inv_size (folded)
    __shared__ float s_iny[NB][GRID];
    __shared__ float s_xmin[NB], s_xmax[NB], s_ymin[NB], s_ymax[NB], s_inv[NB];

    const int n0 = pb * NB;

    // ---- A1: bbox per net, 8 lanes per net, threads 0..255 only ----
    if (t < 256) {
        const int nl = t >> 3;      // local net 0..31
        const int j  = t & 7;       // pin slot
        const int n  = n0 + nl;
        int pi = (n < NNET) ? net_to_pin[n * MAXPIN + j] : -1;
        int sp = pi > 0 ? pi : 0;
        int v  = pin_to_macro[sp];
        float px = positions[(b * NV + v) * 2 + 0] + pin_offsets[sp * 2 + 0];
        float py = positions[(b * NV + v) * 2 + 1] + pin_offsets[sp * 2 + 1];
        bool valid = pi >= 0;
        float xmx = valid ? px : -1e9f;
        float xmn = valid ? px :  1e9f;
        float ymx = valid ? py : -1e9f;
        float ymn = valid ? py :  1e9f;
        #pragma unroll
        for (int off = 1; off < 8; off <<= 1) {
            xmx = fmaxf(xmx, __shfl_xor(xmx, off, 64));
            xmn = fminf(xmn, __shfl_xor(xmn, off, 64));
            ymx = fmaxf(ymx, __shfl_xor(ymx, off, 64));
            ymn = fminf(ymn, __shfl_xor(ymn, off, 64));
        }
        if (j == 0) {
            float xming = (xmn + 1.0f) * 31.5f;   // (v+1)*0.5*(M-1)
            float xmaxg = (xmx + 1.0f) * 31.5f;
            float yming = (ymn + 1.0f) * 31.5f;
            float ymaxg = (ymx + 1.0f) * 31.5f;
            float size = fmaxf((xmaxg - xming + 1.0f) * (ymaxg - yming + 1.0f), 1.0f);
            s_xmin[nl] = xming; s_xmax[nl] = xmaxg;
            s_ymin[nl] = yming; s_ymax[nl] = ymaxg;
            s_inv[nl]  = 1.0f / size;
        }
    }
    __syncthreads();

    // ---- A2: fill in_x (scaled by inv) / in_y — 4096 vals, 8 per thread ----
    #pragma unroll
    for (int i = 0; i < 8; ++i) {
        int vv    = i * 512 + t;
        int n     = vv >> 7;          // net
        int rem   = vv & 127;
        int which = rem >> 6;         // 0 = x, 1 = y
        int coord = rem & 63;
        float c  = (float)coord;
        float lo = which ? s_ymin[n] : s_xmin[n];
        float hi = which ? s_ymax[n] : s_xmax[n];
        float val = sig2(2.0f * (c - lo + 0.5f), 2.0f * (hi - c + 0.5f));
        if (which) s_iny[n][coord] = val;
        else       s_inx[n][coord] = val * s_inv[n];
    }
    __syncthreads();

    // ---- C: rank-1 accumulate, 8 cells/thread over 32 nets ----
    const int lane = t & 63;        // x coordinate
    const int w    = t >> 6;        // wave id 0..7: rows y = w*8 .. w*8+7
    float acc[8];
    #pragma unroll
    for (int k = 0; k < 8; ++k) acc[k] = 0.0f;

    for (int n = 0; n < NB; ++n) {
        float xv = s_inx[n][lane];
        const float4* iny4 = (const float4*)&s_iny[n][w * 8];  // 32B aligned
        #pragma unroll
        for (int k4 = 0; k4 < 2; ++k4) {
            float4 yv = iny4[k4];
            acc[k4 * 4 + 0] += yv.x * xv;
            acc[k4 * 4 + 1] += yv.y * xv;
            acc[k4 * 4 + 2] += yv.z * xv;
            acc[k4 * 4 + 3] += yv.w * xv;
        }
    }

    // ---- plain coalesced store of this block's private partial ----
    float* dst = partial + ((size_t)b * NPART + pb) * CELLS;
    #pragma unroll
    for (int k = 0; k < 8; ++k)
        dst[(w * 8 + k) * GRID + lane] = acc[k];
}

// Stage B: grid (8, BATCH) x 256 threads. Block q owns output rows
// y0=q*8..q*8+7. It reduces its 14-row halo slice (rows y0-3..y0+10) across
// the 63 partials, runs the separable 7-tap Gaussian in LDS, writes its 8
// rows of out_smooth, and atomically adds its penalty share.
#define SROWS 14           // 8 output rows + 3 halo each side
__global__ __launch_bounds__(256)
void reduce_smooth_penalty_kernel(const float* __restrict__ partial,
                                  float* __restrict__ out_penalty,
                                  float* __restrict__ out_smooth) {
    const int q = blockIdx.x;       // row slice 0..7
    const int b = blockIdx.y;
    const int t = threadIdx.x;
    const int y0 = q * 8;

    __shared__ float tile[SROWS][GRID];
    __shared__ float tmp [SROWS][GRID];
    __shared__ float red [4];

    // 1D gaussian, sigma=1.5, ksize=7, normalized (separable == normalized 2D)
    float g[7];
    {
        float s = 0.0f;
        #pragma unroll
        for (int i = 0; i < 7; ++i) {
            float d = (float)(i - 3);
            g[i] = expf(-d * d / 4.5f);
            s += g[i];
        }
        float inv = 1.0f / s;
        #pragma unroll
        for (int i = 0; i < 7; ++i) g[i] *= inv;
    }

    // ---- reduce slice across 63 partials: 14 rows x 16 float4 = 224 f4 ----
    if (t < SROWS * 16) {
        const int r  = t >> 4;          // slice row 0..13
        const int c4 = t & 15;          // float4 column
        const int yy = y0 - 3 + r;      // global row (may be out of range)
        float4 a0 = {0,0,0,0}, a1 = {0,0,0,0}, a2 = {0,0,0,0}, a3 = {0,0,0,0};
        if (yy >= 0 && yy < GRID) {
            const float4* src = (const float4*)(partial + (size_t)b * NPART * CELLS)
                                + (size_t)yy * 16 + c4;
            int p = 0;
            for (; p + 3 < NPART; p += 4) {          // 4 independent chains
                float4 v0 = src[(size_t)(p + 0) * (CELLS / 4)];
                float4 v1 = src[(size_t)(p + 1) * (CELLS / 4)];
                float4 v2 = src[(size_t)(p + 2) * (CELLS / 4)];
                float4 v3 = src[(size_t)(p + 3) * (CELLS / 4)];
                a0.x += v0.x; a0.y += v0.y; a0.z += v0.z; a0.w += v0.w;
                a1.x += v1.x; a1.y += v1.y; a1.z += v1.z; a1.w += v1.w;
                a2.x += v2.x; a2.y += v2.y; a2.z += v2.z; a2.w += v2.w;
                a3.x += v3.x; a3.y += v3.y; a3.z += v3.z; a3.w += v3.w;
            }
            for (; p < NPART; ++p) {
                float4 v0 = src[(size_t)p * (CELLS / 4)];
                a0.x += v0.x; a0.y += v0.y; a0.z += v0.z; a0.w += v0.w;
            }
            a0.x += a1.x + a2.x + a3.x;
            a0.y += a1.y + a2.y + a3.y;
            a0.z += a1.z + a2.z + a3.z;
            a0.w += a1.w + a2.w + a3.w;
        }
        ((float4*)&tile[r][0])[c4] = a0;    // zeros for out-of-range rows
    }
    __syncthreads();

    // ---- horizontal pass (zero x-padding): 14*64 = 896 cells ----
    for (int i = t; i < SROWS * GRID; i += 256) {
        int r = i >> 6, x = i & 63;
        float s = 0.0f;
        #pragma unroll
        for (int d = -3; d <= 3; ++d) {
            int xx = x + d;
            if (xx >= 0 && xx < GRID) s += g[d + 3] * tile[r][xx];
        }
        tmp[r][x] = s;
    }
    __syncthreads();

    // ---- vertical pass on the 8 center rows + outputs + penalty ----
    float local = 0.0f;
    #pragma unroll
    for (int i = 0; i < 2; ++i) {
        int c = i * 256 + t;            // 0..511
        int r = c >> 6, x = c & 63;     // r = 0..7
        float s = 0.0f;
        #pragma unroll
        for (int d = -3; d <= 3; ++d)
            s += g[d + 3] * tmp[r + 3 + d][x];   // halo rows already zeroed
        out_smooth[b * CELLS + (y0 + r) * GRID + x] = s;
        float ov = s - 1.0f;
        ov = ov > 0.0f ? ov : 0.0f;
        local += ov * ov;
    }

    #pragma unroll
    for (int off = 32; off > 0; off >>= 1) local += __shfl_down(local, off, 64);
    if ((t & 63) == 0) red[t >> 6] = local;
    __syncthreads();
    if (t == 0)
        atomicAdd(&out_penalty[b], red[0] + red[1] + red[2] + red[3]);
}

extern "C" void kernel_launch(void* const* d_in, const int* in_sizes, int n_in,
                              void* d_out, int out_size, void* d_ws, size_t ws_size,
                              hipStream_t stream) {
    const float* positions    = (const float*)d_in[0];
    const float* pin_offsets  = (const float*)d_in[1];
    const int*   net_to_pin   = (const int*)d_in[2];
    const int*   pin_to_macro = (const int*)d_in[3];
    float* out     = (float*)d_out;        // [0..3] penalty, [4..] rudy_smooth
    float* partial = (float*)d_ws;         // BATCH * NPART * 4096 f32 (~4 MB)

    rudy_partial_kernel<<<dim3(NPART, BATCH), 512, 0, stream>>>(
        positions, pin_offsets, net_to_pin, pin_to_macro, partial, out);
    reduce_smooth_penalty_kernel<<<dim3(8, BATCH), 256, 0, stream>>>(
        partial, out, out + BATCH);
}